// Round 4
// baseline (220.537 us; speedup 1.0000x reference)
//
#include <hip/hip_runtime.h>
#include <hip/hip_bf16.h>

// AdjustedNonLocalBlock: 3x conv1x1 -> attention(S=4096,D=64,B=4) -> conv1x1 + residual.
// fp32 I/O; bf16 internals for MFMA.
//
// Pipeline (3 launches):
//   1. conv_in:  theta(x1)->Q (log2e folded), phi(x0)->K, g(x0)->Vt   (bf16 in ws)
//               16-deep double-buffered channel prefetch; 16 outputs/thread; 768 blocks.
//   2. attn:    S^T = K*Q^T (mfma 16x16x32 bf16); P=2^S b64-packed into LDS;
//               O += P*V; no-max softmax (logits bounded); ksplit=8 -> 2 waves/SIMD.
//   3. conv_out: ysum = sum_ks Opart (FIXED unpack: 8 uint4/row, y[v*8+..]);
//               out = (W*ysum)*(1/sum_ks Lp) + Wb + x0.

typedef unsigned int   u32;
typedef unsigned short u16;
typedef __attribute__((ext_vector_type(8))) short short8;   // 8x bf16 = 4 VGPR (MFMA A/B frag)
typedef __attribute__((ext_vector_type(4))) float f32x4;    // MFMA C/D frag

#define LOG2E 1.4426950408889634f
#define KSPLIT 8

__device__ __forceinline__ float b2f(u16 v) {
  union { u32 u; float f; } x; x.u = ((u32)v) << 16; return x.f;
}
__device__ __forceinline__ u16 f2b(float f) {   // round-to-nearest
  u32 u = __float_as_uint(f);
  return (u16)((u + 0x8000u) >> 16);
}

// ---------------- workspace layout (bytes) ----------------
// Q    [4][4096][64]  bf16 @ 0      (2 MB)
// K    [4][4096][64]  bf16 @ 2 MB   (2 MB)
// Vt   [4][64][4096]  bf16 @ 4 MB   (2 MB)
// Opart[8ks][4][4096][64] bf16 @ 6 MB (16 MB)
// Lp   [8ks][4][4096] f32  @ 22 MB  (512 KB)   -> ~22.5 MB (ws ~268 MB)

// grid (16 n-tiles, 3 convs * 4 o-quarters, 4 batches), block 256. Thread = 1 pixel, 16 outputs.
__global__ __launch_bounds__(256) void conv_in_kernel(
    const float* __restrict__ x0, const float* __restrict__ x1,
    const float* __restrict__ tw, const float* __restrict__ tb,
    const float* __restrict__ pw, const float* __restrict__ pb,
    const float* __restrict__ gw, const float* __restrict__ gb,
    u16* __restrict__ Q, u16* __restrict__ K, u16* __restrict__ Vt)
{
  const int n    = blockIdx.x * 256 + threadIdx.x;
  const int conv = blockIdx.y >> 2;   // 0=theta(x1), 1=phi(x0), 2=g(x0)
  const int oq   = blockIdx.y & 3;    // 16-output quarter
  const int b    = blockIdx.z;

  const float* src  = (conv == 0) ? x1 : x0;
  const float* w    = ((conv == 0) ? tw : (conv == 1) ? pw : gw) + (oq * 16) * 128;
  const float* bias = ((conv == 0) ? tb : (conv == 1) ? pb : gb) + oq * 16;

  float acc[16];
  #pragma unroll
  for (int oo = 0; oo < 16; ++oo) acc[oo] = bias[oo];

  const float* xcol = src + (size_t)b * 128 * 4096 + n;

  float cur[16], nxt[16];
  #pragma unroll
  for (int i = 0; i < 16; ++i) cur[i] = xcol[(size_t)i * 4096];

  #pragma unroll
  for (int cc = 0; cc < 128; cc += 16) {
    if (cc + 16 < 128) {
      #pragma unroll
      for (int i = 0; i < 16; ++i) nxt[i] = xcol[(size_t)(cc + 16 + i) * 4096];
    }
    #pragma unroll
    for (int i = 0; i < 16; ++i) {
      #pragma unroll
      for (int oo = 0; oo < 16; ++oo)
        acc[oo] = fmaf(w[oo * 128 + cc + i], cur[i], acc[oo]);
    }
    #pragma unroll
    for (int i = 0; i < 16; ++i) cur[i] = nxt[i];
  }

  if (conv < 2) {
    const float scale = (conv == 0) ? LOG2E : 1.f;   // fold log2(e) so exp == v_exp_f32
    u16* dst = (conv == 0 ? Q : K) + ((size_t)b * 4096 + n) * 64 + oq * 16;
    u32 wd[8];
    #pragma unroll
    for (int i = 0; i < 8; ++i)
      wd[i] = (u32)f2b(acc[2 * i] * scale) | ((u32)f2b(acc[2 * i + 1] * scale) << 16);
    ((uint4*)dst)[0] = make_uint4(wd[0], wd[1], wd[2], wd[3]);
    ((uint4*)dst)[1] = make_uint4(wd[4], wd[5], wd[6], wd[7]);
  } else {
    u16* dst = Vt + (size_t)b * 64 * 4096 + n;   // transposed, coalesced over n
    #pragma unroll
    for (int oo = 0; oo < 16; ++oo)
      dst[(size_t)(oq * 16 + oo) * 4096] = f2b(acc[oo]);
  }
}

// grid (16 q-tiles of 256, 4 batches, 8 ksplits), block 256 = 4 waves; wave owns 64 q-rows.
__global__ __launch_bounds__(256) void attn_kernel(
    const u16* __restrict__ Q, const u16* __restrict__ K,
    const u16* __restrict__ Vt, u16* __restrict__ Opart,
    float* __restrict__ Lp)
{
  const int qt = blockIdx.x, b = blockIdx.y, ks = blockIdx.z;
  const int tid  = threadIdx.x;
  const int wave = tid >> 6;
  const int lane = tid & 63;
  const int quad = lane >> 4;
  const int l15  = lane & 15;

  __shared__ __align__(16) u16 P_lds[4][64][72];   // per-wave [q][k], +8 pad
  u16* pw = &P_lds[wave][0][0];

  const int q0 = qt * 256 + wave * 64;
  const u16* Qb = Q  + (size_t)b * 4096 * 64;
  const u16* Kb = K  + (size_t)b * 4096 * 64;
  const u16* Vb = Vt + (size_t)b * 64 * 4096;

  // Q fragments (B operand of S^T)
  short8 qf[4][2];
  #pragma unroll
  for (int nt = 0; nt < 4; ++nt) {
    const u16* qp = Qb + (size_t)(q0 + nt * 16 + l15) * 64 + quad * 8;
    qf[nt][0] = *(const short8*)qp;
    qf[nt][1] = *(const short8*)(qp + 32);
  }

  f32x4 oacc[4][4];   // [mq][nd]
  #pragma unroll
  for (int i = 0; i < 4; ++i)
    #pragma unroll
    for (int j = 0; j < 4; ++j)
      oacc[i][j] = (f32x4){0.f, 0.f, 0.f, 0.f};
  float lsum[4] = {0.f, 0.f, 0.f, 0.f};

  const int kbase = ks * (4096 / KSPLIT);
  const int NKT   = 4096 / KSPLIT / 64;   // 8 k-tiles of 64

  short8 kf[4][2];
  #pragma unroll
  for (int mt = 0; mt < 4; ++mt) {
    const u16* kp = Kb + (size_t)(kbase + mt * 16 + l15) * 64 + quad * 8;
    kf[mt][0] = *(const short8*)kp;
    kf[mt][1] = *(const short8*)(kp + 32);
  }

  for (int kt = 0; kt < NKT; ++kt) {
    const int k0 = kbase + kt * 64;

    short8 vf[4][2];
    #pragma unroll
    for (int nd = 0; nd < 4; ++nd) {
      const u16* vp = Vb + (size_t)(nd * 16 + l15) * 4096 + k0 + quad * 8;
      vf[nd][0] = *(const short8*)vp;
      vf[nd][1] = *(const short8*)(vp + 32);
    }

    // S^T tiles, exp2, pack, write P[q][k] to LDS
    #pragma unroll
    for (int mt = 0; mt < 4; ++mt) {
      #pragma unroll
      for (int nt = 0; nt < 4; ++nt) {
        f32x4 s = {0.f, 0.f, 0.f, 0.f};
        s = __builtin_amdgcn_mfma_f32_16x16x32_bf16(kf[mt][0], qf[nt][0], s, 0, 0, 0);
        s = __builtin_amdgcn_mfma_f32_16x16x32_bf16(kf[mt][1], qf[nt][1], s, 0, 0, 0);
        float p0 = exp2f(s[0]), p1 = exp2f(s[1]), p2 = exp2f(s[2]), p3 = exp2f(s[3]);
        lsum[nt] += (p0 + p1) + (p2 + p3);
        u32 u0 = __float_as_uint(p0) + 0x8000u;
        u32 u1 = __float_as_uint(p1) + 0x8000u;
        u32 u2 = __float_as_uint(p2) + 0x8000u;
        u32 u3 = __float_as_uint(p3) + 0x8000u;
        uint2 pk;
        pk.x = __builtin_amdgcn_perm(u1, u0, 0x07060302u);
        pk.y = __builtin_amdgcn_perm(u3, u2, 0x07060302u);
        *(uint2*)(pw + (nt * 16 + l15) * 72 + mt * 16 + quad * 4) = pk;
      }
    }

    if (kt < NKT - 1) {
      #pragma unroll
      for (int mt = 0; mt < 4; ++mt) {
        const u16* kp = Kb + (size_t)(k0 + 64 + mt * 16 + l15) * 64 + quad * 8;
        kf[mt][0] = *(const short8*)kp;
        kf[mt][1] = *(const short8*)(kp + 32);
      }
    }

    // O += P*V
    #pragma unroll
    for (int mq = 0; mq < 4; ++mq) {
      const u16* pr = pw + (mq * 16 + l15) * 72 + quad * 8;
      short8 pa0 = *(const short8*)pr;
      short8 pa1 = *(const short8*)(pr + 32);
      #pragma unroll
      for (int nd = 0; nd < 4; ++nd) {
        oacc[mq][nd] = __builtin_amdgcn_mfma_f32_16x16x32_bf16(pa0, vf[nd][0], oacc[mq][nd], 0, 0, 0);
        oacc[mq][nd] = __builtin_amdgcn_mfma_f32_16x16x32_bf16(pa1, vf[nd][1], oacc[mq][nd], 0, 0, 0);
      }
    }
  }

  // complete row sums across the 4 quads (disjoint k subsets)
  #pragma unroll
  for (int nt = 0; nt < 4; ++nt) {
    float v = lsum[nt];
    v += __shfl_xor(v, 16, 64);
    v += __shfl_xor(v, 32, 64);
    lsum[nt] = v;
  }
  float* LpB = Lp + ((size_t)ks * 4 + b) * 4096;
  if (quad == 0) {
    #pragma unroll
    for (int nt = 0; nt < 4; ++nt)
      LpB[q0 + nt * 16 + l15] = lsum[nt];
  }

  // unnormalized partial O, bf16: O[q = q0+mq*16+quad*4+r][d = nd*16+l15]
  u16* Ob = Opart + ((size_t)ks * 4 + b) * 4096 * 64;
  #pragma unroll
  for (int mq = 0; mq < 4; ++mq)
    #pragma unroll
    for (int nd = 0; nd < 4; ++nd)
      #pragma unroll
      for (int r = 0; r < 4; ++r) {
        int q = q0 + mq * 16 + quad * 4 + r;
        Ob[(size_t)q * 64 + nd * 16 + l15] = f2b(oacc[mq][nd][r]);
      }
}

// grid (16 n-tiles, 4 o-quarters, 4 batches). Fused combine + conv_out.
// Row = 64 bf16 = 8 uint4; each uint4 = 8 consecutive bf16 -> y[v*8 + 0..7].
__global__ __launch_bounds__(256) void conv_out_kernel(
    const u16* __restrict__ Opart, const float* __restrict__ Lp,
    const float* __restrict__ Wf, const float* __restrict__ Wbf,
    const float* __restrict__ x0, float* __restrict__ out)
{
  const int n  = blockIdx.x * 256 + threadIdx.x;
  const int oq = blockIdx.y;
  const int b  = blockIdx.z;

  float l = 0.f;
  float y[64];
  #pragma unroll
  for (int i = 0; i < 64; ++i) y[i] = 0.f;

  #pragma unroll
  for (int ks = 0; ks < KSPLIT; ++ks) {
    l += Lp[((size_t)ks * 4 + b) * 4096 + n];
    const uint4* orow = (const uint4*)(Opart + (((size_t)ks * 4 + b) * 4096 + n) * 64);
    #pragma unroll
    for (int v = 0; v < 8; ++v) {
      uint4 r = orow[v];
      u32 wds[4] = {r.x, r.y, r.z, r.w};
      #pragma unroll
      for (int j = 0; j < 4; ++j) {
        y[v * 8 + 2 * j]     += __uint_as_float(wds[j] << 16);
        y[v * 8 + 2 * j + 1] += __uint_as_float(wds[j] & 0xffff0000u);
      }
    }
  }
  const float rinv = 1.f / l;

  const float* wq = Wf + (oq * 32) * 64;   // W_w[o][ci]
  float acc[32];
  #pragma unroll
  for (int oo = 0; oo < 32; ++oo) acc[oo] = 0.f;

  #pragma unroll 8
  for (int ci = 0; ci < 64; ++ci) {
    float yv = y[ci];
    #pragma unroll
    for (int oo = 0; oo < 32; ++oo)
      acc[oo] = fmaf(wq[oo * 64 + ci], yv, acc[oo]);
  }

  #pragma unroll
  for (int oo = 0; oo < 32; ++oo) {
    int o = oq * 32 + oo;
    size_t idx = ((size_t)(b * 128 + o)) * 4096 + n;
    out[idx] = fmaf(acc[oo], rinv, Wbf[o]) + x0[idx];
  }
}

extern "C" void kernel_launch(void* const* d_in, const int* in_sizes, int n_in,
                              void* d_out, int out_size, void* d_ws, size_t ws_size,
                              hipStream_t stream) {
  const float* x0 = (const float*)d_in[0];
  const float* x1 = (const float*)d_in[1];
  const float* gw = (const float*)d_in[2];
  const float* gb = (const float*)d_in[3];
  const float* tw = (const float*)d_in[4];
  const float* tb = (const float*)d_in[5];
  const float* pw = (const float*)d_in[6];
  const float* pb = (const float*)d_in[7];
  const float* Ww = (const float*)d_in[8];
  const float* Wb = (const float*)d_in[9];
  float* out = (float*)d_out;

  char* ws = (char*)d_ws;
  u16*   Qw    = (u16*)(ws + 0);
  u16*   Kw    = (u16*)(ws + (2u << 20));
  u16*   Vtw   = (u16*)(ws + (4u << 20));
  u16*   Opart = (u16*)(ws + (6u << 20));
  float* Lp    = (float*)(ws + (22u << 20));   // ~22.5 MB total

  conv_in_kernel<<<dim3(16, 12, 4), dim3(256), 0, stream>>>(
      x0, x1, tw, tb, pw, pb, gw, gb, Qw, Kw, Vtw);

  attn_kernel<<<dim3(16, 4, KSPLIT), dim3(256), 0, stream>>>(Qw, Kw, Vtw, Opart, Lp);

  conv_out_kernel<<<dim3(16, 4, 4), dim3(256), 0, stream>>>(
      Opart, Lp, Ww, Wb, x0, out);
}

// Round 5
// 174.718 us; speedup vs baseline: 1.2622x; 1.2622x over previous
//
#include <hip/hip_runtime.h>
#include <hip/hip_bf16.h>

// AdjustedNonLocalBlock: 3x conv1x1 -> attention(S=4096,D=64,B=4) -> conv1x1 + residual.
// fp32 I/O; bf16 internals for MFMA.
//
// Pipeline (4 launches):
//   1. conv_in:  theta(x1)->Q (log2e folded), phi(x0)->K, g(x0)->Vt   (bf16)  [unchanged R4]
//   2. attn:     S^T = K*Q^T; P=2^S b64-packed to LDS; O += P*V; ksplit=8    [unchanged R4]
//   3. combine:  Y = sum_ks(Opart)/sum_ks(Lp), uint2-vectorized, 1024 blocks
//   4. proj:     out = W*Y + Wb + x0; 8 outs/thread, 1024 blocks (low VGPR, 16 waves/CU)

typedef unsigned int   u32;
typedef unsigned short u16;
typedef __attribute__((ext_vector_type(8))) short short8;   // 8x bf16 = 4 VGPR (MFMA A/B frag)
typedef __attribute__((ext_vector_type(4))) float f32x4;    // MFMA C/D frag

#define LOG2E 1.4426950408889634f
#define KSPLIT 8

__device__ __forceinline__ float b2f(u16 v) {
  union { u32 u; float f; } x; x.u = ((u32)v) << 16; return x.f;
}
__device__ __forceinline__ u16 f2b(float f) {   // round-to-nearest
  u32 u = __float_as_uint(f);
  return (u16)((u + 0x8000u) >> 16);
}

// ---------------- workspace layout (bytes) ----------------
// Q    [4][4096][64]  bf16 @ 0       (2 MB)
// K    [4][4096][64]  bf16 @ 2 MB    (2 MB)
// Vt   [4][64][4096]  bf16 @ 4 MB    (2 MB)
// Opart[8ks][4][4096][64] bf16 @ 6 MB (16 MB)
// Lp   [8ks][4][4096] f32  @ 22 MB   (512 KB)
// Y    [4][4096][64]  bf16 @ 22.5 MB (2 MB)    -> ~24.5 MB

// grid (16 n-tiles, 3 convs * 4 o-quarters, 4 batches), block 256. Thread = 1 pixel, 16 outputs.
__global__ __launch_bounds__(256) void conv_in_kernel(
    const float* __restrict__ x0, const float* __restrict__ x1,
    const float* __restrict__ tw, const float* __restrict__ tb,
    const float* __restrict__ pw, const float* __restrict__ pb,
    const float* __restrict__ gw, const float* __restrict__ gb,
    u16* __restrict__ Q, u16* __restrict__ K, u16* __restrict__ Vt)
{
  const int n    = blockIdx.x * 256 + threadIdx.x;
  const int conv = blockIdx.y >> 2;   // 0=theta(x1), 1=phi(x0), 2=g(x0)
  const int oq   = blockIdx.y & 3;    // 16-output quarter
  const int b    = blockIdx.z;

  const float* src  = (conv == 0) ? x1 : x0;
  const float* w    = ((conv == 0) ? tw : (conv == 1) ? pw : gw) + (oq * 16) * 128;
  const float* bias = ((conv == 0) ? tb : (conv == 1) ? pb : gb) + oq * 16;

  float acc[16];
  #pragma unroll
  for (int oo = 0; oo < 16; ++oo) acc[oo] = bias[oo];

  const float* xcol = src + (size_t)b * 128 * 4096 + n;

  float cur[16], nxt[16];
  #pragma unroll
  for (int i = 0; i < 16; ++i) cur[i] = xcol[(size_t)i * 4096];

  #pragma unroll
  for (int cc = 0; cc < 128; cc += 16) {
    if (cc + 16 < 128) {
      #pragma unroll
      for (int i = 0; i < 16; ++i) nxt[i] = xcol[(size_t)(cc + 16 + i) * 4096];
    }
    #pragma unroll
    for (int i = 0; i < 16; ++i) {
      #pragma unroll
      for (int oo = 0; oo < 16; ++oo)
        acc[oo] = fmaf(w[oo * 128 + cc + i], cur[i], acc[oo]);
    }
    #pragma unroll
    for (int i = 0; i < 16; ++i) cur[i] = nxt[i];
  }

  if (conv < 2) {
    const float scale = (conv == 0) ? LOG2E : 1.f;   // fold log2(e) so exp == v_exp_f32
    u16* dst = (conv == 0 ? Q : K) + ((size_t)b * 4096 + n) * 64 + oq * 16;
    u32 wd[8];
    #pragma unroll
    for (int i = 0; i < 8; ++i)
      wd[i] = (u32)f2b(acc[2 * i] * scale) | ((u32)f2b(acc[2 * i + 1] * scale) << 16);
    ((uint4*)dst)[0] = make_uint4(wd[0], wd[1], wd[2], wd[3]);
    ((uint4*)dst)[1] = make_uint4(wd[4], wd[5], wd[6], wd[7]);
  } else {
    u16* dst = Vt + (size_t)b * 64 * 4096 + n;   // transposed, coalesced over n
    #pragma unroll
    for (int oo = 0; oo < 16; ++oo)
      dst[(size_t)(oq * 16 + oo) * 4096] = f2b(acc[oo]);
  }
}

// grid (16 q-tiles of 256, 4 batches, 8 ksplits), block 256 = 4 waves; wave owns 64 q-rows.
__global__ __launch_bounds__(256) void attn_kernel(
    const u16* __restrict__ Q, const u16* __restrict__ K,
    const u16* __restrict__ Vt, u16* __restrict__ Opart,
    float* __restrict__ Lp)
{
  const int qt = blockIdx.x, b = blockIdx.y, ks = blockIdx.z;
  const int tid  = threadIdx.x;
  const int wave = tid >> 6;
  const int lane = tid & 63;
  const int quad = lane >> 4;
  const int l15  = lane & 15;

  __shared__ __align__(16) u16 P_lds[4][64][72];   // per-wave [q][k], +8 pad
  u16* pw = &P_lds[wave][0][0];

  const int q0 = qt * 256 + wave * 64;
  const u16* Qb = Q  + (size_t)b * 4096 * 64;
  const u16* Kb = K  + (size_t)b * 4096 * 64;
  const u16* Vb = Vt + (size_t)b * 64 * 4096;

  // Q fragments (B operand of S^T)
  short8 qf[4][2];
  #pragma unroll
  for (int nt = 0; nt < 4; ++nt) {
    const u16* qp = Qb + (size_t)(q0 + nt * 16 + l15) * 64 + quad * 8;
    qf[nt][0] = *(const short8*)qp;
    qf[nt][1] = *(const short8*)(qp + 32);
  }

  f32x4 oacc[4][4];   // [mq][nd]
  #pragma unroll
  for (int i = 0; i < 4; ++i)
    #pragma unroll
    for (int j = 0; j < 4; ++j)
      oacc[i][j] = (f32x4){0.f, 0.f, 0.f, 0.f};
  float lsum[4] = {0.f, 0.f, 0.f, 0.f};

  const int kbase = ks * (4096 / KSPLIT);
  const int NKT   = 4096 / KSPLIT / 64;   // 8 k-tiles of 64

  short8 kf[4][2];
  #pragma unroll
  for (int mt = 0; mt < 4; ++mt) {
    const u16* kp = Kb + (size_t)(kbase + mt * 16 + l15) * 64 + quad * 8;
    kf[mt][0] = *(const short8*)kp;
    kf[mt][1] = *(const short8*)(kp + 32);
  }

  for (int kt = 0; kt < NKT; ++kt) {
    const int k0 = kbase + kt * 64;

    short8 vf[4][2];
    #pragma unroll
    for (int nd = 0; nd < 4; ++nd) {
      const u16* vp = Vb + (size_t)(nd * 16 + l15) * 4096 + k0 + quad * 8;
      vf[nd][0] = *(const short8*)vp;
      vf[nd][1] = *(const short8*)(vp + 32);
    }

    // S^T tiles, exp2, pack, write P[q][k] to LDS
    #pragma unroll
    for (int mt = 0; mt < 4; ++mt) {
      #pragma unroll
      for (int nt = 0; nt < 4; ++nt) {
        f32x4 s = {0.f, 0.f, 0.f, 0.f};
        s = __builtin_amdgcn_mfma_f32_16x16x32_bf16(kf[mt][0], qf[nt][0], s, 0, 0, 0);
        s = __builtin_amdgcn_mfma_f32_16x16x32_bf16(kf[mt][1], qf[nt][1], s, 0, 0, 0);
        float p0 = exp2f(s[0]), p1 = exp2f(s[1]), p2 = exp2f(s[2]), p3 = exp2f(s[3]);
        lsum[nt] += (p0 + p1) + (p2 + p3);
        u32 u0 = __float_as_uint(p0) + 0x8000u;
        u32 u1 = __float_as_uint(p1) + 0x8000u;
        u32 u2 = __float_as_uint(p2) + 0x8000u;
        u32 u3 = __float_as_uint(p3) + 0x8000u;
        uint2 pk;
        pk.x = __builtin_amdgcn_perm(u1, u0, 0x07060302u);
        pk.y = __builtin_amdgcn_perm(u3, u2, 0x07060302u);
        *(uint2*)(pw + (nt * 16 + l15) * 72 + mt * 16 + quad * 4) = pk;
      }
    }

    if (kt < NKT - 1) {
      #pragma unroll
      for (int mt = 0; mt < 4; ++mt) {
        const u16* kp = Kb + (size_t)(k0 + 64 + mt * 16 + l15) * 64 + quad * 8;
        kf[mt][0] = *(const short8*)kp;
        kf[mt][1] = *(const short8*)(kp + 32);
      }
    }

    // O += P*V
    #pragma unroll
    for (int mq = 0; mq < 4; ++mq) {
      const u16* pr = pw + (mq * 16 + l15) * 72 + quad * 8;
      short8 pa0 = *(const short8*)pr;
      short8 pa1 = *(const short8*)(pr + 32);
      #pragma unroll
      for (int nd = 0; nd < 4; ++nd) {
        oacc[mq][nd] = __builtin_amdgcn_mfma_f32_16x16x32_bf16(pa0, vf[nd][0], oacc[mq][nd], 0, 0, 0);
        oacc[mq][nd] = __builtin_amdgcn_mfma_f32_16x16x32_bf16(pa1, vf[nd][1], oacc[mq][nd], 0, 0, 0);
      }
    }
  }

  // complete row sums across the 4 quads (disjoint k subsets)
  #pragma unroll
  for (int nt = 0; nt < 4; ++nt) {
    float v = lsum[nt];
    v += __shfl_xor(v, 16, 64);
    v += __shfl_xor(v, 32, 64);
    lsum[nt] = v;
  }
  float* LpB = Lp + ((size_t)ks * 4 + b) * 4096;
  if (quad == 0) {
    #pragma unroll
    for (int nt = 0; nt < 4; ++nt)
      LpB[q0 + nt * 16 + l15] = lsum[nt];
  }

  // unnormalized partial O, bf16: O[q = q0+mq*16+quad*4+r][d = nd*16+l15]
  u16* Ob = Opart + ((size_t)ks * 4 + b) * 4096 * 64;
  #pragma unroll
  for (int mq = 0; mq < 4; ++mq)
    #pragma unroll
    for (int nd = 0; nd < 4; ++nd)
      #pragma unroll
      for (int r = 0; r < 4; ++r) {
        int q = q0 + mq * 16 + quad * 4 + r;
        Ob[(size_t)q * 64 + nd * 16 + l15] = f2b(oacc[mq][nd][r]);
      }
}

// grid 1024 blocks x 256. One thread = 4 consecutive channels (one uint2) of one (b,q) row.
// Y = sum_ks(Opart) / sum_ks(Lp), bf16.
__global__ __launch_bounds__(256) void combine_kernel(
    const u16* __restrict__ Opart, const float* __restrict__ Lp,
    u16* __restrict__ Y)
{
  int idx = blockIdx.x * 256 + threadIdx.x;   // over 4*4096*16 uint2
  int i2 = idx & 15;          // uint2 index within the 64-ch row
  int bq = idx >> 4;          // b*4096 + q

  float a0 = 0.f, a1 = 0.f, a2 = 0.f, a3 = 0.f, l = 0.f;
  #pragma unroll
  for (int ks = 0; ks < KSPLIT; ++ks) {
    const uint2* row = (const uint2*)(Opart + ((size_t)ks * 4 * 4096 + bq) * 64);
    uint2 r = row[i2];
    a0 += __uint_as_float(r.x << 16);
    a1 += __uint_as_float(r.x & 0xffff0000u);
    a2 += __uint_as_float(r.y << 16);
    a3 += __uint_as_float(r.y & 0xffff0000u);
    l  += Lp[(size_t)ks * 4 * 4096 + bq];
  }
  const float rinv = 1.f / l;
  uint2 o;
  o.x = (u32)f2b(a0 * rinv) | ((u32)f2b(a1 * rinv) << 16);
  o.y = (u32)f2b(a2 * rinv) | ((u32)f2b(a3 * rinv) << 16);
  ((uint2*)Y)[(size_t)bq * 16 + i2] = o;
}

// grid (16 n-tiles, 16 o-octets, 4 batches) = 1024 blocks. Thread = 1 pixel, 8 outputs.
// Low VGPR (~64) -> high occupancy; W/bias reads are block-uniform -> s_load.
__global__ __launch_bounds__(256) void proj_kernel(
    const u16* __restrict__ Y, const float* __restrict__ Wf,
    const float* __restrict__ Wbf, const float* __restrict__ x0,
    float* __restrict__ out)
{
  const int n  = blockIdx.x * 256 + threadIdx.x;
  const int og = blockIdx.y;   // 8-output group
  const int b  = blockIdx.z;

  uint4 yraw[8];
  const u16* yrow = Y + ((size_t)b * 4096 + n) * 64;
  #pragma unroll
  for (int v = 0; v < 8; ++v) yraw[v] = ((const uint4*)yrow)[v];
  const u16* yu = (const u16*)yraw;

  const float* wq = Wf + (og * 8) * 64;   // W_w[o][ci]
  float acc[8];
  #pragma unroll
  for (int oo = 0; oo < 8; ++oo) acc[oo] = Wbf[og * 8 + oo];

  #pragma unroll 8
  for (int ci = 0; ci < 64; ++ci) {
    float yv = b2f(yu[ci]);
    #pragma unroll
    for (int oo = 0; oo < 8; ++oo)
      acc[oo] = fmaf(wq[oo * 64 + ci], yv, acc[oo]);
  }

  #pragma unroll
  for (int oo = 0; oo < 8; ++oo) {
    int o = og * 8 + oo;
    size_t idx = ((size_t)(b * 128 + o)) * 4096 + n;
    out[idx] = acc[oo] + x0[idx];
  }
}

extern "C" void kernel_launch(void* const* d_in, const int* in_sizes, int n_in,
                              void* d_out, int out_size, void* d_ws, size_t ws_size,
                              hipStream_t stream) {
  const float* x0 = (const float*)d_in[0];
  const float* x1 = (const float*)d_in[1];
  const float* gw = (const float*)d_in[2];
  const float* gb = (const float*)d_in[3];
  const float* tw = (const float*)d_in[4];
  const float* tb = (const float*)d_in[5];
  const float* pw = (const float*)d_in[6];
  const float* pb = (const float*)d_in[7];
  const float* Ww = (const float*)d_in[8];
  const float* Wb = (const float*)d_in[9];
  float* out = (float*)d_out;

  char* ws = (char*)d_ws;
  u16*   Qw    = (u16*)(ws + 0);
  u16*   Kw    = (u16*)(ws + (2u << 20));
  u16*   Vtw   = (u16*)(ws + (4u << 20));
  u16*   Opart = (u16*)(ws + (6u << 20));
  float* Lp    = (float*)(ws + (22u << 20));
  u16*   Yw    = (u16*)(ws + (22u << 20) + (512u << 10));   // ~24.5 MB total

  conv_in_kernel<<<dim3(16, 12, 4), dim3(256), 0, stream>>>(
      x0, x1, tw, tb, pw, pb, gw, gb, Qw, Kw, Vtw);

  attn_kernel<<<dim3(16, 4, KSPLIT), dim3(256), 0, stream>>>(Qw, Kw, Vtw, Opart, Lp);

  combine_kernel<<<dim3(1024), dim3(256), 0, stream>>>(Opart, Lp, Yw);

  proj_kernel<<<dim3(16, 16, 4), dim3(256), 0, stream>>>(Yw, Ww, Wb, x0, out);
}

// Round 8
// 160.073 us; speedup vs baseline: 1.3777x; 1.0915x over previous
//
#include <hip/hip_runtime.h>
#include <hip/hip_bf16.h>

// AdjustedNonLocalBlock: 3x conv1x1 -> attention(S=4096,D=64,B=4) -> conv1x1 + residual.
// fp32 I/O; bf16 internals for MFMA.
//
// Pipeline (6 launches):
//   1. cast_w:    tw/pw/gw fp32 -> bf16 wb (tw pre-scaled by log2e)
//   2. transpose: x0,x1 [b][128][4096] fp32 -> xT [b][4096][128] bf16 (LDS tile)
//   3. conv_mfma: Q/K = xT*w^T -> [n][64]; Vt = w*xT^T -> [64][n] (operand swap, all b128)
//   4. attn:      S^T = K*Q^T; P=2^S packed to LDS (short4 stores — same TBAA family as
//                 short8 reads; compiler fences around the phase boundary); O += P*V; ksplit=8
//   5. combine:   Y = sum_ks(Opart)/sum_ks(Lp)
//   6. proj:      out = W*Y + Wb + x0

typedef unsigned int   u32;
typedef unsigned short u16;
typedef __attribute__((ext_vector_type(8))) short short8;   // 8x bf16 = 4 VGPR (MFMA A/B frag)
typedef __attribute__((ext_vector_type(4))) short short4v;  // 4x bf16 (LDS P store)
typedef __attribute__((ext_vector_type(4))) float f32x4;    // MFMA C/D frag

#define LOG2E 1.4426950408889634f
#define KSPLIT 8

__device__ __forceinline__ float b2f(u16 v) {
  union { u32 u; float f; } x; x.u = ((u32)v) << 16; return x.f;
}
__device__ __forceinline__ u16 f2b(float f) {   // round-to-nearest
  u32 u = __float_as_uint(f);
  return (u16)((u + 0x8000u) >> 16);
}

// ---------------- workspace layout (bytes) ----------------
// x0T  [4][4096][128] bf16 @ 0     (4 MB)
// x1T  [4][4096][128] bf16 @ 4 MB  (4 MB)
// wb   [3][64][128]   bf16 @ 8 MB  (48 KB)
// Q    [4][4096][64]  bf16 @ 9 MB  (2 MB)
// K    [4][4096][64]  bf16 @ 11 MB (2 MB)
// Vt   [4][64][4096]  bf16 @ 13 MB (2 MB)
// Opart[8][4][4096][64] bf16 @ 15 MB (16 MB)
// Lp   [8][4][4096] f32 @ 31 MB    (512 KB)
// Y    [4][4096][64] bf16 @ 31.5 MB (2 MB)   -> ~33.5 MB

__global__ __launch_bounds__(256) void cast_w_kernel(
    const float* __restrict__ tw, const float* __restrict__ pw,
    const float* __restrict__ gw, u16* __restrict__ wb)
{
  int i = blockIdx.x * 256 + threadIdx.x;
  if (i >= 24576) return;
  float v;
  if      (i < 8192)  v = tw[i] * LOG2E;
  else if (i < 16384) v = pw[i - 8192];
  else                v = gw[i - 16384];
  wb[i] = f2b(v);
}

// grid (16 n-tiles of 256, 2 c-halves of 64, b*2+tensor), block 256.
__global__ __launch_bounds__(256) void transpose_kernel(
    const float* __restrict__ x0, const float* __restrict__ x1,
    u16* __restrict__ x0T, u16* __restrict__ x1T)
{
  const int n0 = blockIdx.x * 256;
  const int c0 = blockIdx.y * 64;
  const int bz = blockIdx.z;
  const int b  = bz >> 1;
  const float* src = (bz & 1) ? x1 : x0;
  u16*         dst = (bz & 1) ? x1T : x0T;

  __shared__ u16 tile[64][266];   // [c][n], +10 pad
  const int t = threadIdx.x;

  const float* sp = src + ((size_t)b * 128 + c0) * 4096 + n0 + t;
  #pragma unroll 16
  for (int i = 0; i < 64; ++i)
    tile[i][t] = f2b(sp[(size_t)i * 4096]);
  asm volatile("" ::: "memory");
  __syncthreads();

  const int sub   = t & 3;    // 16-c chunk
  const int nbase = t >> 2;   // 0..63
  #pragma unroll
  for (int g = 0; g < 4; ++g) {
    const int nn = nbase + g * 64;   // all 256 n rows covered
    u16 vals[16];
    #pragma unroll
    for (int j = 0; j < 16; ++j) vals[j] = tile[sub * 16 + j][nn];
    u32 wd[8];
    #pragma unroll
    for (int j = 0; j < 8; ++j)
      wd[j] = (u32)vals[2 * j] | ((u32)vals[2 * j + 1] << 16);
    u16* dp = dst + ((size_t)(b * 4096 + n0 + nn)) * 128 + c0 + sub * 16;
    ((uint4*)dp)[0] = make_uint4(wd[0], wd[1], wd[2], wd[3]);
    ((uint4*)dp)[1] = make_uint4(wd[4], wd[5], wd[6], wd[7]);
  }
}

// grid (32 n-tiles of 128, 3 convs, 4 batches), block 128 = 2 waves; wave owns 64 n.
__global__ __launch_bounds__(128) void conv_mfma_kernel(
    const u16* __restrict__ x0T, const u16* __restrict__ x1T,
    const u16* __restrict__ wb,
    const float* __restrict__ tb, const float* __restrict__ pb,
    const float* __restrict__ gb,
    u16* __restrict__ Q, u16* __restrict__ K, u16* __restrict__ Vt)
{
  const int conv = blockIdx.y;
  const int b    = blockIdx.z;
  const int wave = threadIdx.x >> 6;
  const int lane = threadIdx.x & 63;
  const int quad = lane >> 4, l15 = lane & 15;
  const int n0   = blockIdx.x * 128 + wave * 64;

  const u16* xT  = (conv == 0) ? x1T : x0T;
  const u16* wbc = wb + conv * 8192;

  f32x4 acc[4][4];
  #pragma unroll
  for (int i = 0; i < 4; ++i)
    #pragma unroll
    for (int j = 0; j < 4; ++j)
      acc[i][j] = (f32x4){0.f, 0.f, 0.f, 0.f};

  #pragma unroll
  for (int kk = 0; kk < 4; ++kk) {
    short8 xf[4], wf[4];
    #pragma unroll
    for (int nt = 0; nt < 4; ++nt)
      xf[nt] = *(const short8*)(xT + (size_t)(b * 4096 + n0 + nt * 16 + l15) * 128 + kk * 32 + quad * 8);
    #pragma unroll
    for (int ot = 0; ot < 4; ++ot)
      wf[ot] = *(const short8*)(wbc + (ot * 16 + l15) * 128 + kk * 32 + quad * 8);
    if (conv < 2) {
      #pragma unroll
      for (int i = 0; i < 4; ++i)
        #pragma unroll
        for (int j = 0; j < 4; ++j)
          acc[i][j] = __builtin_amdgcn_mfma_f32_16x16x32_bf16(xf[i], wf[j], acc[i][j], 0, 0, 0);
    } else {
      #pragma unroll
      for (int i = 0; i < 4; ++i)
        #pragma unroll
        for (int j = 0; j < 4; ++j)
          acc[i][j] = __builtin_amdgcn_mfma_f32_16x16x32_bf16(wf[i], xf[j], acc[i][j], 0, 0, 0);
    }
  }

  if (conv < 2) {
    // C[row=n][col=o]
    u16* dst = (conv == 0 ? Q : K) + (size_t)b * 4096 * 64;
    const float* bias = (conv == 0) ? tb : pb;
    const float bscale = (conv == 0) ? LOG2E : 1.f;
    #pragma unroll
    for (int ot = 0; ot < 4; ++ot) {
      const float bv = bias[ot * 16 + l15] * bscale;
      #pragma unroll
      for (int nt = 0; nt < 4; ++nt)
        #pragma unroll
        for (int r = 0; r < 4; ++r) {
          int n = n0 + nt * 16 + quad * 4 + r;
          dst[(size_t)n * 64 + ot * 16 + l15] = f2b(acc[nt][ot][r] + bv);
        }
    }
  } else {
    // C[row=o][col=n]
    u16* dst = Vt + (size_t)b * 64 * 4096;
    #pragma unroll
    for (int orr = 0; orr < 4; ++orr)
      #pragma unroll
      for (int r = 0; r < 4; ++r) {
        const int o = orr * 16 + quad * 4 + r;
        const float bv = gb[o];
        #pragma unroll
        for (int nc = 0; nc < 4; ++nc)
          dst[(size_t)o * 4096 + n0 + nc * 16 + l15] = f2b(acc[orr][nc][r] + bv);
      }
  }
}

// grid (16 q-tiles of 256, 4 batches, 8 ksplits), block 256 = 4 waves; wave owns 64 q-rows.
__global__ __launch_bounds__(256) void attn_kernel(
    const u16* __restrict__ Q, const u16* __restrict__ K,
    const u16* __restrict__ Vt, u16* __restrict__ Opart,
    float* __restrict__ Lp)
{
  const int qt = blockIdx.x, b = blockIdx.y, ks = blockIdx.z;
  const int tid  = threadIdx.x;
  const int wave = tid >> 6;
  const int lane = tid & 63;
  const int quad = lane >> 4;
  const int l15  = lane & 15;

  __shared__ __align__(16) short P_lds[4][64][72];   // per-wave [q][k], +8 pad
  short* pw = &P_lds[wave][0][0];

  const int q0 = qt * 256 + wave * 64;
  const u16* Qb = Q  + (size_t)b * 4096 * 64;
  const u16* Kb = K  + (size_t)b * 4096 * 64;
  const u16* Vb = Vt + (size_t)b * 64 * 4096;

  short8 qf[4][2];
  #pragma unroll
  for (int nt = 0; nt < 4; ++nt) {
    const u16* qp = Qb + (size_t)(q0 + nt * 16 + l15) * 64 + quad * 8;
    qf[nt][0] = *(const short8*)qp;
    qf[nt][1] = *(const short8*)(qp + 32);
  }

  f32x4 oacc[4][4];
  #pragma unroll
  for (int i = 0; i < 4; ++i)
    #pragma unroll
    for (int j = 0; j < 4; ++j)
      oacc[i][j] = (f32x4){0.f, 0.f, 0.f, 0.f};
  float lsum[4] = {0.f, 0.f, 0.f, 0.f};

  const int kbase = ks * (4096 / KSPLIT);
  const int NKT   = 4096 / KSPLIT / 64;

  short8 kf[4][2];
  #pragma unroll
  for (int mt = 0; mt < 4; ++mt) {
    const u16* kp = Kb + (size_t)(kbase + mt * 16 + l15) * 64 + quad * 8;
    kf[mt][0] = *(const short8*)kp;
    kf[mt][1] = *(const short8*)(kp + 32);
  }

  for (int kt = 0; kt < NKT; ++kt) {
    const int k0 = kbase + kt * 64;

    short8 vf[4][2];
    #pragma unroll
    for (int nd = 0; nd < 4; ++nd) {
      const u16* vp = Vb + (size_t)(nd * 16 + l15) * 4096 + k0 + quad * 8;
      vf[nd][0] = *(const short8*)vp;
      vf[nd][1] = *(const short8*)(vp + 32);
    }

    // S^T tiles, exp2, pack, write P[q][k] to LDS (short4 stores, 4 consecutive k/lane)
    #pragma unroll
    for (int mt = 0; mt < 4; ++mt) {
      #pragma unroll
      for (int nt = 0; nt < 4; ++nt) {
        f32x4 s = {0.f, 0.f, 0.f, 0.f};
        s = __builtin_amdgcn_mfma_f32_16x16x32_bf16(kf[mt][0], qf[nt][0], s, 0, 0, 0);
        s = __builtin_amdgcn_mfma_f32_16x16x32_bf16(kf[mt][1], qf[nt][1], s, 0, 0, 0);
        float p0 = exp2f(s[0]), p1 = exp2f(s[1]), p2 = exp2f(s[2]), p3 = exp2f(s[3]);
        lsum[nt] += (p0 + p1) + (p2 + p3);
        u32 u0 = __float_as_uint(p0) + 0x8000u;
        u32 u1 = __float_as_uint(p1) + 0x8000u;
        u32 u2 = __float_as_uint(p2) + 0x8000u;
        u32 u3 = __float_as_uint(p3) + 0x8000u;
        union { uint2 u; short4v s4; } pk;
        pk.u.x = __builtin_amdgcn_perm(u1, u0, 0x07060302u);
        pk.u.y = __builtin_amdgcn_perm(u3, u2, 0x07060302u);
        *(short4v*)(pw + (nt * 16 + l15) * 72 + mt * 16 + quad * 4) = pk.s4;
      }
    }

    if (kt < NKT - 1) {
      #pragma unroll
      for (int mt = 0; mt < 4; ++mt) {
        const u16* kp = Kb + (size_t)(k0 + 64 + mt * 16 + l15) * 64 + quad * 8;
        kf[mt][0] = *(const short8*)kp;
        kf[mt][1] = *(const short8*)(kp + 32);
      }
    }

    asm volatile("" ::: "memory");   // S-phase LDS writes ordered before PV-phase reads

    #pragma unroll
    for (int mq = 0; mq < 4; ++mq) {
      const short* pr = pw + (mq * 16 + l15) * 72 + quad * 8;
      short8 pa0 = *(const short8*)pr;
      short8 pa1 = *(const short8*)(pr + 32);
      #pragma unroll
      for (int nd = 0; nd < 4; ++nd) {
        oacc[mq][nd] = __builtin_amdgcn_mfma_f32_16x16x32_bf16(pa0, vf[nd][0], oacc[mq][nd], 0, 0, 0);
        oacc[mq][nd] = __builtin_amdgcn_mfma_f32_16x16x32_bf16(pa1, vf[nd][1], oacc[mq][nd], 0, 0, 0);
      }
    }

    asm volatile("" ::: "memory");   // PV reads complete before next kt overwrites P
  }

  #pragma unroll
  for (int nt = 0; nt < 4; ++nt) {
    float v = lsum[nt];
    v += __shfl_xor(v, 16, 64);
    v += __shfl_xor(v, 32, 64);
    lsum[nt] = v;
  }
  float* LpB = Lp + ((size_t)ks * 4 + b) * 4096;
  if (quad == 0) {
    #pragma unroll
    for (int nt = 0; nt < 4; ++nt)
      LpB[q0 + nt * 16 + l15] = lsum[nt];
  }

  u16* Ob = Opart + ((size_t)ks * 4 + b) * 4096 * 64;
  #pragma unroll
  for (int mq = 0; mq < 4; ++mq)
    #pragma unroll
    for (int nd = 0; nd < 4; ++nd)
      #pragma unroll
      for (int r = 0; r < 4; ++r) {
        int q = q0 + mq * 16 + quad * 4 + r;
        Ob[(size_t)q * 64 + nd * 16 + l15] = f2b(oacc[mq][nd][r]);
      }
}

// grid 1024 x 256. Thread = one uint2 (4 channels) of one (b,q) row.
__global__ __launch_bounds__(256) void combine_kernel(
    const u16* __restrict__ Opart, const float* __restrict__ Lp,
    u16* __restrict__ Y)
{
  int idx = blockIdx.x * 256 + threadIdx.x;
  int i2 = idx & 15;
  int bq = idx >> 4;

  float a0 = 0.f, a1 = 0.f, a2 = 0.f, a3 = 0.f, l = 0.f;
  #pragma unroll
  for (int ks = 0; ks < KSPLIT; ++ks) {
    const uint2* row = (const uint2*)(Opart + ((size_t)ks * 4 * 4096 + bq) * 64);
    uint2 r = row[i2];
    a0 += __uint_as_float(r.x << 16);
    a1 += __uint_as_float(r.x & 0xffff0000u);
    a2 += __uint_as_float(r.y << 16);
    a3 += __uint_as_float(r.y & 0xffff0000u);
    l  += Lp[(size_t)ks * 4 * 4096 + bq];
  }
  const float rinv = 1.f / l;
  uint2 o;
  o.x = (u32)f2b(a0 * rinv) | ((u32)f2b(a1 * rinv) << 16);
  o.y = (u32)f2b(a2 * rinv) | ((u32)f2b(a3 * rinv) << 16);
  ((uint2*)Y)[(size_t)bq * 16 + i2] = o;
}

// grid (16 n-tiles, 16 o-octets, 4 batches). Thread = 1 pixel, 8 outputs.
__global__ __launch_bounds__(256) void proj_kernel(
    const u16* __restrict__ Y, const float* __restrict__ Wf,
    const float* __restrict__ Wbf, const float* __restrict__ x0,
    float* __restrict__ out)
{
  const int n  = blockIdx.x * 256 + threadIdx.x;
  const int og = blockIdx.y;
  const int b  = blockIdx.z;

  uint4 yraw[8];
  const u16* yrow = Y + ((size_t)b * 4096 + n) * 64;
  #pragma unroll
  for (int v = 0; v < 8; ++v) yraw[v] = ((const uint4*)yrow)[v];
  const u16* yu = (const u16*)yraw;

  const float* wq = Wf + (og * 8) * 64;
  float acc[8];
  #pragma unroll
  for (int oo = 0; oo < 8; ++oo) acc[oo] = Wbf[og * 8 + oo];

  #pragma unroll 8
  for (int ci = 0; ci < 64; ++ci) {
    float yv = b2f(yu[ci]);
    #pragma unroll
    for (int oo = 0; oo < 8; ++oo)
      acc[oo] = fmaf(wq[oo * 64 + ci], yv, acc[oo]);
  }

  #pragma unroll
  for (int oo = 0; oo < 8; ++oo) {
    int o = og * 8 + oo;
    size_t idx = ((size_t)(b * 128 + o)) * 4096 + n;
    out[idx] = acc[oo] + x0[idx];
  }
}

extern "C" void kernel_launch(void* const* d_in, const int* in_sizes, int n_in,
                              void* d_out, int out_size, void* d_ws, size_t ws_size,
                              hipStream_t stream) {
  const float* x0 = (const float*)d_in[0];
  const float* x1 = (const float*)d_in[1];
  const float* gw = (const float*)d_in[2];
  const float* gb = (const float*)d_in[3];
  const float* tw = (const float*)d_in[4];
  const float* tb = (const float*)d_in[5];
  const float* pw = (const float*)d_in[6];
  const float* pb = (const float*)d_in[7];
  const float* Ww = (const float*)d_in[8];
  const float* Wb = (const float*)d_in[9];
  float* out = (float*)d_out;

  char* ws = (char*)d_ws;
  u16*   x0T   = (u16*)(ws + 0);
  u16*   x1T   = (u16*)(ws + (4u << 20));
  u16*   wbuf  = (u16*)(ws + (8u << 20));
  u16*   Qw    = (u16*)(ws + (9u << 20));
  u16*   Kw    = (u16*)(ws + (11u << 20));
  u16*   Vtw   = (u16*)(ws + (13u << 20));
  u16*   Opart = (u16*)(ws + (15u << 20));
  float* Lp    = (float*)(ws + (31u << 20));
  u16*   Yw    = (u16*)(ws + (31u << 20) + (512u << 10));   // ~33.5 MB total

  cast_w_kernel<<<dim3(96), dim3(256), 0, stream>>>(tw, pw, gw, wbuf);

  transpose_kernel<<<dim3(16, 2, 8), dim3(256), 0, stream>>>(x0, x1, x0T, x1T);

  conv_mfma_kernel<<<dim3(32, 3, 4), dim3(128), 0, stream>>>(
      x0T, x1T, wbuf, tb, pb, gb, Qw, Kw, Vtw);

  attn_kernel<<<dim3(16, 4, KSPLIT), dim3(256), 0, stream>>>(Qw, Kw, Vtw, Opart, Lp);

  combine_kernel<<<dim3(1024), dim3(256), 0, stream>>>(Opart, Lp, Yw);

  proj_kernel<<<dim3(16, 16, 4), dim3(256), 0, stream>>>(Yw, Ww, Wb, x0, out);
}

// Round 9
// 136.000 us; speedup vs baseline: 1.6216x; 1.1770x over previous
//
#include <hip/hip_runtime.h>
#include <hip/hip_bf16.h>

// AdjustedNonLocalBlock: 3x conv1x1 -> attention(S=4096,D=64,B=4) -> conv1x1 + residual.
// fp32 I/O; bf16 internals for MFMA. 3-kernel pipeline (launch overhead matters):
//   1. qkv_fused: x0/x1 -> LDS (bf16, transposed) -> MFMA convs -> Q[n][64], K[n][64], Vt[64][n]
//   2. attn:      S^T = K*Q^T; P=2^S -> LDS; O += P*V; no-max softmax; ksplit=8  [verified]
//   3. out_fused: Ysum/L -> LDS; MFMA proj C[o][n] = W*Y; + Wb + x0 residual

typedef unsigned int   u32;
typedef unsigned short u16;
typedef __attribute__((ext_vector_type(8))) short short8;   // 8x bf16 (MFMA A/B frag)
typedef __attribute__((ext_vector_type(4))) short short4v;  // 4x bf16 (LDS P store)
typedef __attribute__((ext_vector_type(4))) float f32x4;    // MFMA C/D frag

#define LOG2E 1.4426950408889634f
#define KSPLIT 8

__device__ __forceinline__ float b2f(u16 v) {
  union { u32 u; float f; } x; x.u = ((u32)v) << 16; return x.f;
}
__device__ __forceinline__ u16 f2b(float f) {
  u32 u = __float_as_uint(f);
  return (u16)((u + 0x8000u) >> 16);
}
// build a short8 bf16 frag from 8 consecutive fp32 (32B-aligned), with scale
__device__ __forceinline__ short8 load_w_frag(const float* p, float s) {
  const float4 f0 = ((const float4*)p)[0];
  const float4 f1 = ((const float4*)p)[1];
  union { u32 w[4]; short8 s8; } r;
  r.w[0] = (u32)f2b(f0.x * s) | ((u32)f2b(f0.y * s) << 16);
  r.w[1] = (u32)f2b(f0.z * s) | ((u32)f2b(f0.w * s) << 16);
  r.w[2] = (u32)f2b(f1.x * s) | ((u32)f2b(f1.y * s) << 16);
  r.w[3] = (u32)f2b(f1.z * s) | ((u32)f2b(f1.w * s) << 16);
  return r.s8;
}

// ---------------- workspace layout (bytes) ----------------
// Q    [4][4096][64]  bf16 @ 0     (2 MB)
// K    [4][4096][64]  bf16 @ 2 MB  (2 MB)
// Vt   [4][64][4096]  bf16 @ 4 MB  (2 MB)
// Opart[8][4][4096][64] bf16 @ 6 MB (16 MB)
// Lp   [8][4][4096] f32 @ 22 MB    (512 KB)  -> 22.5 MB

// grid (64 n-tiles of 64, 4 batches), block 256 = 4 waves.
// Stage x0,x1 [128c][64n] -> LDS xt[tensor][n][c] bf16; then per-wave MFMA convs.
// wave0: theta(x1)->Q, wave1: phi(x0)->K, wave2/3: g(x0)->Vt (o-halves).
__global__ __launch_bounds__(256) void qkv_fused_kernel(
    const float* __restrict__ x0, const float* __restrict__ x1,
    const float* __restrict__ tw, const float* __restrict__ tb,
    const float* __restrict__ pw, const float* __restrict__ pb,
    const float* __restrict__ gw, const float* __restrict__ gb,
    u16* __restrict__ Q, u16* __restrict__ K, u16* __restrict__ Vt)
{
  const int n0 = blockIdx.x * 64;
  const int b  = blockIdx.y;
  const int t  = threadIdx.x;

  __shared__ __align__(16) short xt[2][64][136];   // [tensor][n][c], +8 pad

  // staging: 16384 bf16 elements, idx = tensor*8192 + c*64 + n  (n fastest -> coalesced)
  #pragma unroll 8
  for (int i = 0; i < 64; ++i) {
    const int idx = i * 256 + t;
    const int tensor = idx >> 13;
    const int c = (idx >> 6) & 127;
    const int n = idx & 63;
    const float v = (tensor ? x1 : x0)[((size_t)b * 128 + c) * 4096 + n0 + n];
    xt[tensor][n][c] = (short)f2b(v);
  }
  asm volatile("" ::: "memory");
  __syncthreads();

  const int wave = t >> 6;
  const int lane = t & 63;
  const int quad = lane >> 4, l15 = lane & 15;

  if (wave < 2) {
    // Q (theta on x1) or K (phi on x0): C[n][o] = mfma(A=x[n][c], B=w[o][c])
    const int conv = wave;
    const float* wsrc = conv ? pw : tw;
    const float  ws   = conv ? 1.f : LOG2E;
    const short* xl   = &xt[conv ? 0 : 1][0][0];

    f32x4 acc[4][4];
    #pragma unroll
    for (int i = 0; i < 4; ++i)
      #pragma unroll
      for (int j = 0; j < 4; ++j) acc[i][j] = (f32x4){0.f, 0.f, 0.f, 0.f};

    #pragma unroll
    for (int kk = 0; kk < 4; ++kk) {
      short8 wf[4], xf[4];
      #pragma unroll
      for (int ot = 0; ot < 4; ++ot)
        wf[ot] = load_w_frag(wsrc + (ot * 16 + l15) * 128 + kk * 32 + quad * 8, ws);
      #pragma unroll
      for (int nt = 0; nt < 4; ++nt)
        xf[nt] = *(const short8*)(xl + (nt * 16 + l15) * 136 + kk * 32 + quad * 8);
      #pragma unroll
      for (int i = 0; i < 4; ++i)
        #pragma unroll
        for (int j = 0; j < 4; ++j)
          acc[i][j] = __builtin_amdgcn_mfma_f32_16x16x32_bf16(xf[i], wf[j], acc[i][j], 0, 0, 0);
    }

    u16* dst = (conv ? K : Q) + (size_t)b * 4096 * 64;
    const float* bias = conv ? pb : tb;
    const float bscale = conv ? 1.f : LOG2E;
    #pragma unroll
    for (int ot = 0; ot < 4; ++ot) {
      const float bv = bias[ot * 16 + l15] * bscale;
      #pragma unroll
      for (int nt = 0; nt < 4; ++nt)
        #pragma unroll
        for (int r = 0; r < 4; ++r) {
          const int n = n0 + nt * 16 + quad * 4 + r;
          dst[(size_t)n * 64 + ot * 16 + l15] = f2b(acc[nt][ot][r] + bv);
        }
    }
  } else {
    // Vt (g on x0): C[o][n] = mfma(A=w[o][c], B=x[n][c]); wave handles 32-o half
    const int oh = wave - 2;
    const short* xl = &xt[0][0][0];

    f32x4 acc[2][4];
    #pragma unroll
    for (int i = 0; i < 2; ++i)
      #pragma unroll
      for (int j = 0; j < 4; ++j) acc[i][j] = (f32x4){0.f, 0.f, 0.f, 0.f};

    #pragma unroll
    for (int kk = 0; kk < 4; ++kk) {
      short8 wf[2], xf[4];
      #pragma unroll
      for (int ot = 0; ot < 2; ++ot)
        wf[ot] = load_w_frag(gw + ((oh * 2 + ot) * 16 + l15) * 128 + kk * 32 + quad * 8, 1.f);
      #pragma unroll
      for (int nt = 0; nt < 4; ++nt)
        xf[nt] = *(const short8*)(xl + (nt * 16 + l15) * 136 + kk * 32 + quad * 8);
      #pragma unroll
      for (int i = 0; i < 2; ++i)
        #pragma unroll
        for (int j = 0; j < 4; ++j)
          acc[i][j] = __builtin_amdgcn_mfma_f32_16x16x32_bf16(wf[i], xf[j], acc[i][j], 0, 0, 0);
    }

    u16* dst = Vt + (size_t)b * 64 * 4096;
    #pragma unroll
    for (int ot = 0; ot < 2; ++ot)
      #pragma unroll
      for (int r = 0; r < 4; ++r) {
        const int o = (oh * 2 + ot) * 16 + quad * 4 + r;
        const float bv = gb[o];
        #pragma unroll
        for (int nc = 0; nc < 4; ++nc)
          dst[(size_t)o * 4096 + n0 + nc * 16 + l15] = f2b(acc[ot][nc][r] + bv);
      }
  }
}

// grid (16 q-tiles of 256, 4 batches, 8 ksplits), block 256 = 4 waves — verified R8 kernel.
__global__ __launch_bounds__(256) void attn_kernel(
    const u16* __restrict__ Q, const u16* __restrict__ K,
    const u16* __restrict__ Vt, u16* __restrict__ Opart,
    float* __restrict__ Lp)
{
  const int qt = blockIdx.x, b = blockIdx.y, ks = blockIdx.z;
  const int tid  = threadIdx.x;
  const int wave = tid >> 6;
  const int lane = tid & 63;
  const int quad = lane >> 4;
  const int l15  = lane & 15;

  __shared__ __align__(16) short P_lds[4][64][72];
  short* pw = &P_lds[wave][0][0];

  const int q0 = qt * 256 + wave * 64;
  const u16* Qb = Q  + (size_t)b * 4096 * 64;
  const u16* Kb = K  + (size_t)b * 4096 * 64;
  const u16* Vb = Vt + (size_t)b * 64 * 4096;

  short8 qf[4][2];
  #pragma unroll
  for (int nt = 0; nt < 4; ++nt) {
    const u16* qp = Qb + (size_t)(q0 + nt * 16 + l15) * 64 + quad * 8;
    qf[nt][0] = *(const short8*)qp;
    qf[nt][1] = *(const short8*)(qp + 32);
  }

  f32x4 oacc[4][4];
  #pragma unroll
  for (int i = 0; i < 4; ++i)
    #pragma unroll
    for (int j = 0; j < 4; ++j)
      oacc[i][j] = (f32x4){0.f, 0.f, 0.f, 0.f};
  float lsum[4] = {0.f, 0.f, 0.f, 0.f};

  const int kbase = ks * (4096 / KSPLIT);
  const int NKT   = 4096 / KSPLIT / 64;

  short8 kf[4][2];
  #pragma unroll
  for (int mt = 0; mt < 4; ++mt) {
    const u16* kp = Kb + (size_t)(kbase + mt * 16 + l15) * 64 + quad * 8;
    kf[mt][0] = *(const short8*)kp;
    kf[mt][1] = *(const short8*)(kp + 32);
  }

  for (int kt = 0; kt < NKT; ++kt) {
    const int k0 = kbase + kt * 64;

    short8 vf[4][2];
    #pragma unroll
    for (int nd = 0; nd < 4; ++nd) {
      const u16* vp = Vb + (size_t)(nd * 16 + l15) * 4096 + k0 + quad * 8;
      vf[nd][0] = *(const short8*)vp;
      vf[nd][1] = *(const short8*)(vp + 32);
    }

    #pragma unroll
    for (int mt = 0; mt < 4; ++mt) {
      #pragma unroll
      for (int nt = 0; nt < 4; ++nt) {
        f32x4 s = {0.f, 0.f, 0.f, 0.f};
        s = __builtin_amdgcn_mfma_f32_16x16x32_bf16(kf[mt][0], qf[nt][0], s, 0, 0, 0);
        s = __builtin_amdgcn_mfma_f32_16x16x32_bf16(kf[mt][1], qf[nt][1], s, 0, 0, 0);
        float p0 = exp2f(s[0]), p1 = exp2f(s[1]), p2 = exp2f(s[2]), p3 = exp2f(s[3]);
        lsum[nt] += (p0 + p1) + (p2 + p3);
        u32 u0 = __float_as_uint(p0) + 0x8000u;
        u32 u1 = __float_as_uint(p1) + 0x8000u;
        u32 u2 = __float_as_uint(p2) + 0x8000u;
        u32 u3 = __float_as_uint(p3) + 0x8000u;
        union { uint2 u; short4v s4; } pk;
        pk.u.x = __builtin_amdgcn_perm(u1, u0, 0x07060302u);
        pk.u.y = __builtin_amdgcn_perm(u3, u2, 0x07060302u);
        *(short4v*)(pw + (nt * 16 + l15) * 72 + mt * 16 + quad * 4) = pk.s4;
      }
    }

    if (kt < NKT - 1) {
      #pragma unroll
      for (int mt = 0; mt < 4; ++mt) {
        const u16* kp = Kb + (size_t)(k0 + 64 + mt * 16 + l15) * 64 + quad * 8;
        kf[mt][0] = *(const short8*)kp;
        kf[mt][1] = *(const short8*)(kp + 32);
      }
    }

    asm volatile("" ::: "memory");

    #pragma unroll
    for (int mq = 0; mq < 4; ++mq) {
      const short* pr = pw + (mq * 16 + l15) * 72 + quad * 8;
      short8 pa0 = *(const short8*)pr;
      short8 pa1 = *(const short8*)(pr + 32);
      #pragma unroll
      for (int nd = 0; nd < 4; ++nd) {
        oacc[mq][nd] = __builtin_amdgcn_mfma_f32_16x16x32_bf16(pa0, vf[nd][0], oacc[mq][nd], 0, 0, 0);
        oacc[mq][nd] = __builtin_amdgcn_mfma_f32_16x16x32_bf16(pa1, vf[nd][1], oacc[mq][nd], 0, 0, 0);
      }
    }

    asm volatile("" ::: "memory");
  }

  #pragma unroll
  for (int nt = 0; nt < 4; ++nt) {
    float v = lsum[nt];
    v += __shfl_xor(v, 16, 64);
    v += __shfl_xor(v, 32, 64);
    lsum[nt] = v;
  }
  float* LpB = Lp + ((size_t)ks * 4 + b) * 4096;
  if (quad == 0) {
    #pragma unroll
    for (int nt = 0; nt < 4; ++nt)
      LpB[q0 + nt * 16 + l15] = lsum[nt];
  }

  u16* Ob = Opart + ((size_t)ks * 4 + b) * 4096 * 64;
  #pragma unroll
  for (int mq = 0; mq < 4; ++mq)
    #pragma unroll
    for (int nd = 0; nd < 4; ++nd)
      #pragma unroll
      for (int r = 0; r < 4; ++r) {
        int q = q0 + mq * 16 + quad * 4 + r;
        Ob[(size_t)q * 64 + nd * 16 + l15] = f2b(oacc[mq][nd][r]);
      }
}

// grid (64 n-tiles of 64, 4 batches), block 256 = 4 waves.
// Phase 1: Y[n][64] = sum_ks(Opart)/sum_ks(Lp) -> LDS bf16. Phase 2: MFMA proj
// C[o][n] = mfma(A=W[o][ci], B=Y[n][ci]); out = C + Wb + x0.
__global__ __launch_bounds__(256) void out_fused_kernel(
    const u16* __restrict__ Opart, const float* __restrict__ Lp,
    const float* __restrict__ Wf, const float* __restrict__ Wbf,
    const float* __restrict__ x0, float* __restrict__ out)
{
  const int n0 = blockIdx.x * 64;
  const int b  = blockIdx.y;
  const int t  = threadIdx.x;

  __shared__ __align__(16) short Ys[64][72];   // [n][ci], +8 pad

  {
    const int nl = t >> 2;          // 0..63
    const int q4 = t & 3;           // 16-ch chunk
    const int ng = n0 + nl;

    float l = 0.f;
    #pragma unroll
    for (int ks = 0; ks < KSPLIT; ++ks)
      l += Lp[((size_t)ks * 4 + b) * 4096 + ng];

    float a[16];
    #pragma unroll
    for (int j = 0; j < 16; ++j) a[j] = 0.f;
    #pragma unroll
    for (int ks = 0; ks < KSPLIT; ++ks) {
      const uint4* row = (const uint4*)(Opart + (((size_t)ks * 4 + b) * 4096 + ng) * 64 + q4 * 16);
      #pragma unroll
      for (int v = 0; v < 2; ++v) {
        uint4 r = row[v];
        u32 wds[4] = {r.x, r.y, r.z, r.w};
        #pragma unroll
        for (int j = 0; j < 4; ++j) {
          a[v * 8 + 2 * j]     += __uint_as_float(wds[j] << 16);
          a[v * 8 + 2 * j + 1] += __uint_as_float(wds[j] & 0xffff0000u);
        }
      }
    }
    const float rinv = 1.f / l;
    union { u32 w[8]; short8 s8[2]; } pk;
    #pragma unroll
    for (int j = 0; j < 8; ++j)
      pk.w[j] = (u32)f2b(a[2 * j] * rinv) | ((u32)f2b(a[2 * j + 1] * rinv) << 16);
    *(short8*)&Ys[nl][q4 * 16]     = pk.s8[0];
    *(short8*)&Ys[nl][q4 * 16 + 8] = pk.s8[1];
  }
  asm volatile("" ::: "memory");
  __syncthreads();

  const int wave = t >> 6;
  const int lane = t & 63;
  const int quad = lane >> 4, l15 = lane & 15;

  f32x4 acc[2][4];   // [o-tile within wave][n-tile]
  #pragma unroll
  for (int i = 0; i < 2; ++i)
    #pragma unroll
    for (int j = 0; j < 4; ++j) acc[i][j] = (f32x4){0.f, 0.f, 0.f, 0.f};

  #pragma unroll
  for (int kk = 0; kk < 2; ++kk) {
    short8 wf[2], yf[4];
    #pragma unroll
    for (int ot = 0; ot < 2; ++ot)
      wf[ot] = load_w_frag(Wf + ((wave * 2 + ot) * 16 + l15) * 64 + kk * 32 + quad * 8, 1.f);
    #pragma unroll
    for (int nt = 0; nt < 4; ++nt)
      yf[nt] = *(const short8*)&Ys[nt * 16 + l15][kk * 32 + quad * 8];
    #pragma unroll
    for (int i = 0; i < 2; ++i)
      #pragma unroll
      for (int j = 0; j < 4; ++j)
        acc[i][j] = __builtin_amdgcn_mfma_f32_16x16x32_bf16(wf[i], yf[j], acc[i][j], 0, 0, 0);
  }

  #pragma unroll
  for (int ot = 0; ot < 2; ++ot)
    #pragma unroll
    for (int r = 0; r < 4; ++r) {
      const int o = (wave * 2 + ot) * 16 + quad * 4 + r;
      const float bv = Wbf[o];
      #pragma unroll
      for (int nt = 0; nt < 4; ++nt) {
        const size_t idx = ((size_t)(b * 128 + o)) * 4096 + n0 + nt * 16 + l15;
        out[idx] = acc[ot][nt][r] + bv + x0[idx];
      }
    }
}

extern "C" void kernel_launch(void* const* d_in, const int* in_sizes, int n_in,
                              void* d_out, int out_size, void* d_ws, size_t ws_size,
                              hipStream_t stream) {
  const float* x0 = (const float*)d_in[0];
  const float* x1 = (const float*)d_in[1];
  const float* gw = (const float*)d_in[2];
  const float* gb = (const float*)d_in[3];
  const float* tw = (const float*)d_in[4];
  const float* tb = (const float*)d_in[5];
  const float* pw = (const float*)d_in[6];
  const float* pb = (const float*)d_in[7];
  const float* Ww = (const float*)d_in[8];
  const float* Wb = (const float*)d_in[9];
  float* out = (float*)d_out;

  char* ws = (char*)d_ws;
  u16*   Qw    = (u16*)(ws + 0);
  u16*   Kw    = (u16*)(ws + (2u << 20));
  u16*   Vtw   = (u16*)(ws + (4u << 20));
  u16*   Opart = (u16*)(ws + (6u << 20));
  float* Lp    = (float*)(ws + (22u << 20));   // 22.5 MB total

  qkv_fused_kernel<<<dim3(64, 4), dim3(256), 0, stream>>>(
      x0, x1, tw, tb, pw, pb, gw, gb, Qw, Kw, Vtw);

  attn_kernel<<<dim3(16, 4, KSPLIT), dim3(256), 0, stream>>>(Qw, Kw, Vtw, Opart, Lp);

  out_fused_kernel<<<dim3(64, 4), dim3(256), 0, stream>>>(
      Opart, Lp, Ww, Wb, x0, out);
}